// Round 7
// baseline (379.070 us; speedup 1.0000x reference)
//
#include <hip/hip_runtime.h>
#include <cstddef>

#define T_LEN 1000
#define B_SZ 64
#define C_IN_ 12
#define D_MODEL_ 128
#define D_INNER_ 256
#define D_STATE_ 16
#define DT_RANK_ 8
#define N_CLS 5

__device__ __forceinline__ float sigmoid_f(float x) {
  if (x >= 0.f) return 1.f / (1.f + expf(-x));
  float e = expf(x);
  return e / (1.f + e);
}
__device__ __forceinline__ float softplus_f(float x) {
  return (x > 0.f) ? (x + log1pf(expf(-x))) : log1pf(expf(x));
}

// K0: (a) h_T[b][k][1024] = (x @ ip_w.T + ip_b) transposed, t-contiguous rows
//     (b) w_p[k/4][n][4]  = in_proj_w rows 0..255 packed k-major
// grid (4, 65): y<64 -> h chunks (250 t each); y==64 -> W pack (k-quarter per x).
__global__ __launch_bounds__(256) void k0_prep(
    const float* __restrict__ x, const float* __restrict__ ip_w,
    const float* __restrict__ ip_b, const float* __restrict__ in_proj_w,
    float* __restrict__ h_T, float* __restrict__ w_p)
{
  if (blockIdx.y == 64) {
    const int k0 = blockIdx.x * 32;
    const int n = threadIdx.x;
#pragma unroll
    for (int kq = 0; kq < 8; ++kq) {
      float4 v = *(const float4*)&in_proj_w[(size_t)n * D_MODEL_ + k0 + kq * 4];
      const int k = k0 + kq * 4;
      w_p[(size_t)(k >> 2) * 1024 + n * 4 + 0] = v.x;
      w_p[(size_t)(k >> 2) * 1024 + n * 4 + 1] = v.y;
      w_p[(size_t)(k >> 2) * 1024 + n * 4 + 2] = v.z;
      w_p[(size_t)(k >> 2) * 1024 + n * 4 + 3] = v.w;
    }
    return;
  }
  const int b = blockIdx.y;
  const int tl = threadIdx.x;
  if (tl >= 250) return;
  const int t = blockIdx.x * 250 + tl;
  float xr[C_IN_];
  {
    const float4* xp = (const float4*)(x + ((size_t)b * T_LEN + t) * C_IN_);
    float4 v0 = xp[0], v1 = xp[1], v2 = xp[2];
    xr[0] = v0.x; xr[1] = v0.y; xr[2] = v0.z;  xr[3] = v0.w;
    xr[4] = v1.x; xr[5] = v1.y; xr[6] = v1.z;  xr[7] = v1.w;
    xr[8] = v2.x; xr[9] = v2.y; xr[10] = v2.z; xr[11] = v2.w;
  }
  for (int k = 0; k < D_MODEL_; ++k) {
    float acc = ip_b[k];
    const float* wr = ip_w + k * C_IN_;   // uniform -> s_load
#pragma unroll
    for (int c = 0; c < C_IN_; ++c) acc += xr[c] * wr[c];
    h_T[(((size_t)b * D_MODEL_ + k) << 10) + t] = acc;
  }
}

// K1 v6: thread = n. acc[67] = xm column t0-3..t0+63 in VGPRs.
// A-operand via wave-uniform s_loads from h_T; B via coalesced b128 from w_p.
// Conv fully thread-local. ZERO LDS, no barriers.
__global__ __launch_bounds__(256) void k1_u(
    const float* __restrict__ h_T, const float* __restrict__ w_p,
    const float* __restrict__ conv_w, const float* __restrict__ conv_b,
    float* __restrict__ u_out)
{
  const int tile = blockIdx.x;   // 0..15  (t0 = 0..960)
  const int b    = blockIdx.y;   // 0..63
  const int t0   = tile * 64;
  const int n    = threadIdx.x;  // output column

  float acc[67];
#pragma unroll
  for (int m = 0; m < 67; ++m) acc[m] = 0.f;

  for (int kk4 = 0; kk4 < 32; ++kk4) {
    const float4 bb4 = *(const float4*)&w_p[(size_t)kk4 * 1024 + n * 4];
#pragma unroll
    for (int c = 0; c < 4; ++c) {
      // uniform address -> scalar loads on the SMEM pipe
      const float* hp = h_T + (((size_t)b * D_MODEL_ + kk4 * 4 + c) << 10) + (t0 - 3);
      const float bbc = (c == 0) ? bb4.x : (c == 1) ? bb4.y : (c == 2) ? bb4.z : bb4.w;
#pragma unroll
      for (int m = 0; m < 67; ++m) acc[m] += hp[m] * bbc;
    }
  }
  if (t0 == 0) { acc[0] = 0.f; acc[1] = 0.f; acc[2] = 0.f; }  // t<0 pad

  const float4 cw = *(const float4*)&conv_w[n * 4];
  const float  cb = conv_b[n];
#pragma unroll
  for (int i = 0; i < 64; ++i) {
    const int t = t0 + i;
    if (t < T_LEN) {
      float s = cb + acc[i] * cw.x + acc[i + 1] * cw.y
                   + acc[i + 2] * cw.z + acc[i + 3] * cw.w;
      u_out[(((size_t)b * T_LEN + t) << 8) + n] = s * sigmoid_f(s);
    }
  }
}

// K3 v5 (unchanged): phase1 dbc = u @ xp[0:24].T; phase2 thread-per-n emits
// delta and du = delta*u, coalesced [t][d] layout.
__global__ __launch_bounds__(256) void k3_delta(
    const float* __restrict__ u, const float* __restrict__ x_proj_w,
    const float* __restrict__ dt_proj_w, const float* __restrict__ dt_proj_b,
    float* __restrict__ delta_out, float* __restrict__ du_out,
    float* __restrict__ bm_out)
{
  __shared__ float4 xp4[24][65];
  __shared__ float dt_s[64][9];

  const int row0 = blockIdx.x * 64;   // 1000 blocks
  const int tid = threadIdx.x;

  for (int f = tid; f < 24 * 64; f += 256) {
    int c = f >> 6, k4 = f & 63;
    xp4[c][k4] = *(const float4*)&x_proj_w[(size_t)c * 256 + k4 * 4];
  }
  const float4 w0 = *(const float4*)&dt_proj_w[(size_t)tid * 8];
  const float4 w1 = *(const float4*)&dt_proj_w[(size_t)tid * 8 + 4];
  const float bias = dt_proj_b[tid];
  __syncthreads();

  // phase 1
  {
    const int r2 = tid >> 3, cg = tid & 7;
    const int ra = 2 * r2;
    const float4* ua4 = (const float4*)(u + (size_t)(row0 + ra) * 256);
    const float4* ub4 = (const float4*)(u + (size_t)(row0 + ra + 1) * 256);
    float a0 = 0.f, a1 = 0.f, a2 = 0.f, b0 = 0.f, b1 = 0.f, b2 = 0.f;
    for (int k4 = 0; k4 < 64; ++k4) {
      float4 a = ua4[k4], b = ub4[k4];
      float4 q0 = xp4[cg * 3 + 0][k4];
      float4 q1 = xp4[cg * 3 + 1][k4];
      float4 q2 = xp4[cg * 3 + 2][k4];
      a0 += a.x * q0.x + a.y * q0.y + a.z * q0.z + a.w * q0.w;
      a1 += a.x * q1.x + a.y * q1.y + a.z * q1.z + a.w * q1.w;
      a2 += a.x * q2.x + a.y * q2.y + a.z * q2.z + a.w * q2.w;
      b0 += b.x * q0.x + b.y * q0.y + b.z * q0.z + b.w * q0.w;
      b1 += b.x * q1.x + b.y * q1.y + b.z * q1.z + b.w * q1.w;
      b2 += b.x * q2.x + b.y * q2.y + b.z * q2.z + b.w * q2.w;
    }
    float va[2][3] = {{a0, a1, a2}, {b0, b1, b2}};
#pragma unroll
    for (int rr = 0; rr < 2; ++rr)
#pragma unroll
      for (int c = 0; c < 3; ++c) {
        int col = cg * 3 + c;
        int row = ra + rr;
        if (col < 8) dt_s[row][col] = va[rr][c];
        else bm_out[((size_t)(row0 + row)) * 16 + (col - 8)] = va[rr][c];
      }
  }
  __syncthreads();

  // phase 2: thread = n; coalesced b32 stores of delta and du
  for (int r = 0; r < 64; ++r) {
    float pre = bias
      + dt_s[r][0] * w0.x + dt_s[r][1] * w0.y + dt_s[r][2] * w0.z + dt_s[r][3] * w0.w
      + dt_s[r][4] * w1.x + dt_s[r][5] * w1.y + dt_s[r][6] * w1.z + dt_s[r][7] * w1.w;
    float dlt = softplus_f(pre);
    size_t o = (size_t)(row0 + r) * 256 + tid;
    float uv = u[o];
    delta_out[o] = dlt;
    du_out[o] = dlt * uv;
  }
}

// K4 v6 (unchanged): NO LDS. thread = (b, d, n); broadcast b32 reads.
__global__ __launch_bounds__(256) void k4_scan(
    const float* __restrict__ delta, const float* __restrict__ du,
    const float* __restrict__ bm, const float* __restrict__ A_log,
    float* __restrict__ state_out)
{
  const int d0 = blockIdx.x * 16;
  const int b  = blockIdx.y;
  const int tid = threadIdx.x;
  const int dl = tid >> 4;
  const int n  = tid & 15;
  const int d  = d0 + dl;

  const float A2 = -expf(A_log[(size_t)d * 16 + n]) * 1.4426950408889634f;
  float s = 0.f;

  const float* dp = delta + (size_t)b * T_LEN * 256 + d;
  const float* xp = du    + (size_t)b * T_LEN * 256 + d;
  const float* bp = bm    + (size_t)b * T_LEN * 16 + n;

  for (int t = 0; t < T_LEN; t += 4) {
    float dv0 = dp[(t + 0) * 256];
    float dv1 = dp[(t + 1) * 256];
    float dv2 = dp[(t + 2) * 256];
    float dv3 = dp[(t + 3) * 256];
    float xv0 = xp[(t + 0) * 256];
    float xv1 = xp[(t + 1) * 256];
    float xv2 = xp[(t + 2) * 256];
    float xv3 = xp[(t + 3) * 256];
    float bv0 = bp[(t + 0) * 16];
    float bv1 = bp[(t + 1) * 16];
    float bv2 = bp[(t + 2) * 16];
    float bv3 = bp[(t + 3) * 16];
    s = exp2f(dv0 * A2) * s + xv0 * bv0;
    s = exp2f(dv1 * A2) * s + xv1 * bv1;
    s = exp2f(dv2 * A2) * s + xv2 * bv2;
    s = exp2f(dv3 * A2) * s + xv3 * bv3;
  }
  state_out[((size_t)b * 256 + d) * 16 + n] = s;
}

// K5: per-batch head (unchanged).
__global__ __launch_bounds__(256) void k5_head(
    const float* __restrict__ x, const float* __restrict__ ip_w,
    const float* __restrict__ ip_b, const float* __restrict__ in_proj_w,
    const float* __restrict__ x_proj_w, const float* __restrict__ u,
    const float* __restrict__ state, const float* __restrict__ D_skip,
    const float* __restrict__ out_proj_w, const float* __restrict__ fc1_w,
    const float* __restrict__ fc1_b, const float* __restrict__ fc2_w,
    const float* __restrict__ fc2_b, float* __restrict__ out)
{
  const int b = blockIdx.x, tid = threadIdx.x;
  __shared__ float hl[128], ul[256], zs[256], cm[16], yv[256], ov[128], hid[64];
  if (tid < 128) {
    float acc = ip_b[tid];
    const float* xr = x + ((size_t)b * T_LEN + (T_LEN - 1)) * C_IN_;
#pragma unroll
    for (int c = 0; c < C_IN_; ++c) acc += xr[c] * ip_w[tid * C_IN_ + c];
    hl[tid] = acc;
  }
  ul[tid] = u[((size_t)b * T_LEN + (T_LEN - 1)) * 256 + tid];
  __syncthreads();
  {
    float acc = 0.f;
    const float* w = in_proj_w + (size_t)(256 + tid) * 128;
    for (int k = 0; k < 128; ++k) acc += hl[k] * w[k];
    zs[tid] = acc * sigmoid_f(acc);
  }
  if (tid < 16) {
    float acc = 0.f;
    const float* w = x_proj_w + (size_t)(24 + tid) * 256;
    for (int k = 0; k < 256; ++k) acc += ul[k] * w[k];
    cm[tid] = acc;
  }
  __syncthreads();
  {
    const float* st = state + ((size_t)b * 256 + tid) * 16;
    float acc = 0.f;
#pragma unroll
    for (int n = 0; n < 16; ++n) acc += st[n] * cm[n];
    yv[tid] = (acc + ul[tid] * D_skip[tid]) * zs[tid];
  }
  __syncthreads();
  if (tid < 128) {
    float acc = 0.f;
    const float* w = out_proj_w + (size_t)tid * 256;
    for (int k = 0; k < 256; ++k) acc += yv[k] * w[k];
    ov[tid] = acc;
  }
  __syncthreads();
  if (tid < 64) {
    float acc = fc1_b[tid];
    const float* w = fc1_w + (size_t)tid * 128;
    for (int k = 0; k < 128; ++k) acc += ov[k] * w[k];
    hid[tid] = fmaxf(acc, 0.f);
  }
  __syncthreads();
  if (tid < N_CLS) {
    float acc = fc2_b[tid];
    const float* w = fc2_w + (size_t)tid * 64;
    for (int k = 0; k < 64; ++k) acc += hid[k] * w[k];
    out[b * N_CLS + tid] = acc;
  }
}

extern "C" void kernel_launch(void* const* d_in, const int* in_sizes, int n_in,
                              void* d_out, int out_size, void* d_ws, size_t ws_size,
                              hipStream_t stream) {
  (void)in_sizes; (void)n_in; (void)out_size; (void)ws_size;
  const float* x         = (const float*)d_in[0];
  const float* ip_w      = (const float*)d_in[1];
  const float* ip_b      = (const float*)d_in[2];
  const float* in_proj_w = (const float*)d_in[3];
  const float* conv_w    = (const float*)d_in[4];
  const float* conv_b    = (const float*)d_in[5];
  const float* x_proj_w  = (const float*)d_in[6];
  const float* dt_proj_w = (const float*)d_in[7];
  const float* dt_proj_b = (const float*)d_in[8];
  const float* A_log     = (const float*)d_in[9];
  const float* D_skip    = (const float*)d_in[10];
  const float* out_proj_w= (const float*)d_in[11];
  const float* fc1_w     = (const float*)d_in[12];
  const float* fc1_b     = (const float*)d_in[13];
  const float* fc2_w     = (const float*)d_in[14];
  const float* fc2_b     = (const float*)d_in[15];
  float* out = (float*)d_out;

  float* u     = (float*)d_ws;                       // 16,384,000 f32
  float* delta = u + (size_t)64000 * 256;            // 16,384,000 f32
  float* du    = delta + (size_t)64000 * 256;        // 16,384,000 f32
  float* bm    = du + (size_t)64000 * 256;           // 1,024,000 f32
  float* state = bm + (size_t)64000 * 16;            // 262,144 f32
  // transient aliases, live only k0..k1 (delta/du written later by k3):
  float* h_T = delta;                                // 64*128*1024 = 8,388,608 f32
  float* w_p = delta + (size_t)8388608;              // 32,768 f32

  k0_prep<<<dim3(4, 65), 256, 0, stream>>>(x, ip_w, ip_b, in_proj_w, h_T, w_p);
  k1_u<<<dim3(16, 64), 256, 0, stream>>>(h_T, w_p, conv_w, conv_b, u);
  k3_delta<<<1000, 256, 0, stream>>>(u, x_proj_w, dt_proj_w, dt_proj_b, delta, du, bm);
  k4_scan<<<dim3(16, 64), 256, 0, stream>>>(delta, du, bm, A_log, state);
  k5_head<<<64, 256, 0, stream>>>(x, ip_w, ip_b, in_proj_w, x_proj_w, u, state,
                                  D_skip, out_proj_w, fc1_w, fc1_b, fc2_w, fc2_b, out);
}

// Round 8
// 378.794 us; speedup vs baseline: 1.0007x; 1.0007x over previous
//
#include <hip/hip_runtime.h>
#include <cstddef>

#define T_LEN 1000
#define B_SZ 64
#define C_IN_ 12
#define D_MODEL_ 128
#define D_INNER_ 256
#define D_STATE_ 16
#define DT_RANK_ 8
#define N_CLS 5

__device__ __forceinline__ float sigmoid_f(float x) {
  if (x >= 0.f) return 1.f / (1.f + expf(-x));
  float e = expf(x);
  return e / (1.f + e);
}
__device__ __forceinline__ float softplus_f(float x) {
  return (x > 0.f) ? (x + log1pf(expf(-x))) : log1pf(expf(x));
}

// K0: (a) h_T[b][k][1024] = (x @ ip_w.T + ip_b) transposed, t-contiguous rows
//     (b) w_p[k/4][n][4]  = in_proj_w rows 0..255 packed k-major
__global__ __launch_bounds__(256) void k0_prep(
    const float* __restrict__ x, const float* __restrict__ ip_w,
    const float* __restrict__ ip_b, const float* __restrict__ in_proj_w,
    float* __restrict__ h_T, float* __restrict__ w_p)
{
  if (blockIdx.y == 64) {
    const int k0 = blockIdx.x * 32;
    const int n = threadIdx.x;
#pragma unroll
    for (int kq = 0; kq < 8; ++kq) {
      float4 v = *(const float4*)&in_proj_w[(size_t)n * D_MODEL_ + k0 + kq * 4];
      const int k = k0 + kq * 4;
      w_p[(size_t)(k >> 2) * 1024 + n * 4 + 0] = v.x;
      w_p[(size_t)(k >> 2) * 1024 + n * 4 + 1] = v.y;
      w_p[(size_t)(k >> 2) * 1024 + n * 4 + 2] = v.z;
      w_p[(size_t)(k >> 2) * 1024 + n * 4 + 3] = v.w;
    }
    return;
  }
  const int b = blockIdx.y;
  const int tl = threadIdx.x;
  if (tl >= 250) return;
  const int t = blockIdx.x * 250 + tl;
  float xr[C_IN_];
  {
    const float4* xp = (const float4*)(x + ((size_t)b * T_LEN + t) * C_IN_);
    float4 v0 = xp[0], v1 = xp[1], v2 = xp[2];
    xr[0] = v0.x; xr[1] = v0.y; xr[2] = v0.z;  xr[3] = v0.w;
    xr[4] = v1.x; xr[5] = v1.y; xr[6] = v1.z;  xr[7] = v1.w;
    xr[8] = v2.x; xr[9] = v2.y; xr[10] = v2.z; xr[11] = v2.w;
  }
  for (int k = 0; k < D_MODEL_; ++k) {
    float acc = ip_b[k];
    const float* wr = ip_w + k * C_IN_;   // uniform -> scalar path
#pragma unroll
    for (int c = 0; c < C_IN_; ++c) acc += xr[c] * wr[c];
    h_T[(((size_t)b * D_MODEL_ + k) << 10) + t] = acc;
  }
}

// K1 v7: thread = n, acc[67] xm column in ARCH VGPRs (launch_bounds(256,1)
// relaxes the allocator -- the R6 44-VGPR allocation put acc in AGPRs and
// tripled VALU with accvgpr copies). A-operand: wave-uniform loads from h_T;
// B-operand: coalesced b128 from w_p. Conv thread-local. Zero LDS.
__global__ __launch_bounds__(256, 1) void k1_u(
    const float* __restrict__ h_T, const float* __restrict__ w_p,
    const float* __restrict__ conv_w, const float* __restrict__ conv_b,
    float* __restrict__ u_out)
{
  const int tile = blockIdx.x;   // 0..15  (t0 = 0..960)
  const int b    = blockIdx.y;   // 0..63
  const int t0   = tile * 64;
  const int n    = threadIdx.x;  // output column

  float acc[67];
#pragma unroll
  for (int m = 0; m < 67; ++m) acc[m] = 0.f;

  for (int kk4 = 0; kk4 < 32; ++kk4) {
    const float4 bb4 = *(const float4*)&w_p[(size_t)kk4 * 1024 + n * 4];
#pragma unroll
    for (int c = 0; c < 4; ++c) {
      // uniform address -> scalar loads on the SMEM pipe
      const float* hp = h_T + (((size_t)b * D_MODEL_ + kk4 * 4 + c) << 10) + (t0 - 3);
      const float bbc = (c == 0) ? bb4.x : (c == 1) ? bb4.y : (c == 2) ? bb4.z : bb4.w;
#pragma unroll
      for (int m = 0; m < 67; ++m) acc[m] += hp[m] * bbc;
    }
  }
  if (t0 == 0) { acc[0] = 0.f; acc[1] = 0.f; acc[2] = 0.f; }  // t<0 pad

  const float4 cw = *(const float4*)&conv_w[n * 4];
  const float  cb = conv_b[n];
#pragma unroll
  for (int i = 0; i < 64; ++i) {
    const int t = t0 + i;
    if (t < T_LEN) {
      float s = cb + acc[i] * cw.x + acc[i + 1] * cw.y
                   + acc[i + 2] * cw.z + acc[i + 3] * cw.w;
      u_out[(((size_t)b * T_LEN + t) << 8) + n] = s * sigmoid_f(s);
    }
  }
}

// K3 v5: phase1 dbc = u @ xp[0:24].T; phase2 thread-per-n emits delta and
// du = delta*u, coalesced [t][d] layout.
__global__ __launch_bounds__(256) void k3_delta(
    const float* __restrict__ u, const float* __restrict__ x_proj_w,
    const float* __restrict__ dt_proj_w, const float* __restrict__ dt_proj_b,
    float* __restrict__ delta_out, float* __restrict__ du_out,
    float* __restrict__ bm_out)
{
  __shared__ float4 xp4[24][65];
  __shared__ float dt_s[64][9];

  const int row0 = blockIdx.x * 64;   // 1000 blocks
  const int tid = threadIdx.x;

  for (int f = tid; f < 24 * 64; f += 256) {
    int c = f >> 6, k4 = f & 63;
    xp4[c][k4] = *(const float4*)&x_proj_w[(size_t)c * 256 + k4 * 4];
  }
  const float4 w0 = *(const float4*)&dt_proj_w[(size_t)tid * 8];
  const float4 w1 = *(const float4*)&dt_proj_w[(size_t)tid * 8 + 4];
  const float bias = dt_proj_b[tid];
  __syncthreads();

  // phase 1
  {
    const int r2 = tid >> 3, cg = tid & 7;
    const int ra = 2 * r2;
    const float4* ua4 = (const float4*)(u + (size_t)(row0 + ra) * 256);
    const float4* ub4 = (const float4*)(u + (size_t)(row0 + ra + 1) * 256);
    float a0 = 0.f, a1 = 0.f, a2 = 0.f, b0 = 0.f, b1 = 0.f, b2 = 0.f;
    for (int k4 = 0; k4 < 64; ++k4) {
      float4 a = ua4[k4], b = ub4[k4];
      float4 q0 = xp4[cg * 3 + 0][k4];
      float4 q1 = xp4[cg * 3 + 1][k4];
      float4 q2 = xp4[cg * 3 + 2][k4];
      a0 += a.x * q0.x + a.y * q0.y + a.z * q0.z + a.w * q0.w;
      a1 += a.x * q1.x + a.y * q1.y + a.z * q1.z + a.w * q1.w;
      a2 += a.x * q2.x + a.y * q2.y + a.z * q2.z + a.w * q2.w;
      b0 += b.x * q0.x + b.y * q0.y + b.z * q0.z + b.w * q0.w;
      b1 += b.x * q1.x + b.y * q1.y + b.z * q1.z + b.w * q1.w;
      b2 += b.x * q2.x + b.y * q2.y + b.z * q2.z + b.w * q2.w;
    }
    float va[2][3] = {{a0, a1, a2}, {b0, b1, b2}};
#pragma unroll
    for (int rr = 0; rr < 2; ++rr)
#pragma unroll
      for (int c = 0; c < 3; ++c) {
        int col = cg * 3 + c;
        int row = ra + rr;
        if (col < 8) dt_s[row][col] = va[rr][c];
        else bm_out[((size_t)(row0 + row)) * 16 + (col - 8)] = va[rr][c];
      }
  }
  __syncthreads();

  // phase 2: thread = n; coalesced b32 stores of delta and du
  for (int r = 0; r < 64; ++r) {
    float pre = bias
      + dt_s[r][0] * w0.x + dt_s[r][1] * w0.y + dt_s[r][2] * w0.z + dt_s[r][3] * w0.w
      + dt_s[r][4] * w1.x + dt_s[r][5] * w1.y + dt_s[r][6] * w1.z + dt_s[r][7] * w1.w;
    float dlt = softplus_f(pre);
    size_t o = (size_t)(row0 + r) * 256 + tid;
    float uv = u[o];
    delta_out[o] = dlt;
    du_out[o] = dlt * uv;
  }
}

// K4 v6: NO LDS. thread = (b, d, n); broadcast b32 reads, 8 steps in flight.
__global__ __launch_bounds__(256) void k4_scan(
    const float* __restrict__ delta, const float* __restrict__ du,
    const float* __restrict__ bm, const float* __restrict__ A_log,
    float* __restrict__ state_out)
{
  const int d0 = blockIdx.x * 16;
  const int b  = blockIdx.y;
  const int tid = threadIdx.x;
  const int dl = tid >> 4;
  const int n  = tid & 15;
  const int d  = d0 + dl;

  const float A2 = -expf(A_log[(size_t)d * 16 + n]) * 1.4426950408889634f;
  float s = 0.f;

  const float* dp = delta + (size_t)b * T_LEN * 256 + d;
  const float* xp = du    + (size_t)b * T_LEN * 256 + d;
  const float* bp = bm    + (size_t)b * T_LEN * 16 + n;

#pragma unroll 2
  for (int t = 0; t < T_LEN; t += 4) {
    float dv0 = dp[(t + 0) * 256];
    float dv1 = dp[(t + 1) * 256];
    float dv2 = dp[(t + 2) * 256];
    float dv3 = dp[(t + 3) * 256];
    float xv0 = xp[(t + 0) * 256];
    float xv1 = xp[(t + 1) * 256];
    float xv2 = xp[(t + 2) * 256];
    float xv3 = xp[(t + 3) * 256];
    float bv0 = bp[(t + 0) * 16];
    float bv1 = bp[(t + 1) * 16];
    float bv2 = bp[(t + 2) * 16];
    float bv3 = bp[(t + 3) * 16];
    s = exp2f(dv0 * A2) * s + xv0 * bv0;
    s = exp2f(dv1 * A2) * s + xv1 * bv1;
    s = exp2f(dv2 * A2) * s + xv2 * bv2;
    s = exp2f(dv3 * A2) * s + xv3 * bv3;
  }
  state_out[((size_t)b * 256 + d) * 16 + n] = s;
}

// K5: per-batch head; weight dot-products via float4 (4x fewer txns).
__global__ __launch_bounds__(256) void k5_head(
    const float* __restrict__ x, const float* __restrict__ ip_w,
    const float* __restrict__ ip_b, const float* __restrict__ in_proj_w,
    const float* __restrict__ x_proj_w, const float* __restrict__ u,
    const float* __restrict__ state, const float* __restrict__ D_skip,
    const float* __restrict__ out_proj_w, const float* __restrict__ fc1_w,
    const float* __restrict__ fc1_b, const float* __restrict__ fc2_w,
    const float* __restrict__ fc2_b, float* __restrict__ out)
{
  const int b = blockIdx.x, tid = threadIdx.x;
  __shared__ float hl[128], ul[256], zs[256], cm[16], yv[256], ov[128], hid[64];
  if (tid < 128) {
    float acc = ip_b[tid];
    const float* xr = x + ((size_t)b * T_LEN + (T_LEN - 1)) * C_IN_;
#pragma unroll
    for (int c = 0; c < C_IN_; ++c) acc += xr[c] * ip_w[tid * C_IN_ + c];
    hl[tid] = acc;
  }
  ul[tid] = u[((size_t)b * T_LEN + (T_LEN - 1)) * 256 + tid];
  __syncthreads();
  {
    float acc = 0.f;
    const float4* w = (const float4*)(in_proj_w + (size_t)(256 + tid) * 128);
    const float4* h4 = (const float4*)hl;
    for (int k = 0; k < 32; ++k) {
      float4 wv = w[k], hv = h4[k];
      acc += hv.x * wv.x + hv.y * wv.y + hv.z * wv.z + hv.w * wv.w;
    }
    zs[tid] = acc * sigmoid_f(acc);
  }
  if (tid < 16) {
    float acc = 0.f;
    const float4* w = (const float4*)(x_proj_w + (size_t)(24 + tid) * 256);
    const float4* u4 = (const float4*)ul;
    for (int k = 0; k < 64; ++k) {
      float4 wv = w[k], uv = u4[k];
      acc += uv.x * wv.x + uv.y * wv.y + uv.z * wv.z + uv.w * wv.w;
    }
    cm[tid] = acc;
  }
  __syncthreads();
  {
    const float* st = state + ((size_t)b * 256 + tid) * 16;
    float acc = 0.f;
#pragma unroll
    for (int n = 0; n < 16; ++n) acc += st[n] * cm[n];
    yv[tid] = (acc + ul[tid] * D_skip[tid]) * zs[tid];
  }
  __syncthreads();
  if (tid < 128) {
    float acc = 0.f;
    const float4* w = (const float4*)(out_proj_w + (size_t)tid * 256);
    const float4* y4 = (const float4*)yv;
    for (int k = 0; k < 64; ++k) {
      float4 wv = w[k], yv4 = y4[k];
      acc += yv4.x * wv.x + yv4.y * wv.y + yv4.z * wv.z + yv4.w * wv.w;
    }
    ov[tid] = acc;
  }
  __syncthreads();
  if (tid < 64) {
    float acc = fc1_b[tid];
    const float4* w = (const float4*)(fc1_w + (size_t)tid * 128);
    const float4* o4 = (const float4*)ov;
    for (int k = 0; k < 32; ++k) {
      float4 wv = w[k], ov4 = o4[k];
      acc += ov4.x * wv.x + ov4.y * wv.y + ov4.z * wv.z + ov4.w * wv.w;
    }
    hid[tid] = fmaxf(acc, 0.f);
  }
  __syncthreads();
  if (tid < N_CLS) {
    float acc = fc2_b[tid];
    const float* w = fc2_w + (size_t)tid * 64;
    for (int k = 0; k < 64; ++k) acc += hid[k] * w[k];
    out[b * N_CLS + tid] = acc;
  }
}

extern "C" void kernel_launch(void* const* d_in, const int* in_sizes, int n_in,
                              void* d_out, int out_size, void* d_ws, size_t ws_size,
                              hipStream_t stream) {
  (void)in_sizes; (void)n_in; (void)out_size; (void)ws_size;
  const float* x         = (const float*)d_in[0];
  const float* ip_w      = (const float*)d_in[1];
  const float* ip_b      = (const float*)d_in[2];
  const float* in_proj_w = (const float*)d_in[3];
  const float* conv_w    = (const float*)d_in[4];
  const float* conv_b    = (const float*)d_in[5];
  const float* x_proj_w  = (const float*)d_in[6];
  const float* dt_proj_w = (const float*)d_in[7];
  const float* dt_proj_b = (const float*)d_in[8];
  const float* A_log     = (const float*)d_in[9];
  const float* D_skip    = (const float*)d_in[10];
  const float* out_proj_w= (const float*)d_in[11];
  const float* fc1_w     = (const float*)d_in[12];
  const float* fc1_b     = (const float*)d_in[13];
  const float* fc2_w     = (const float*)d_in[14];
  const float* fc2_b     = (const float*)d_in[15];
  float* out = (float*)d_out;

  float* u     = (float*)d_ws;                       // 16,384,000 f32
  float* delta = u + (size_t)64000 * 256;            // 16,384,000 f32
  float* du    = delta + (size_t)64000 * 256;        // 16,384,000 f32
  float* bm    = du + (size_t)64000 * 256;           // 1,024,000 f32
  float* state = bm + (size_t)64000 * 16;            // 262,144 f32
  // transient aliases, live only k0..k1 (delta/du written later by k3):
  float* h_T = delta;                                // 64*128*1024 = 8,388,608 f32
  float* w_p = delta + (size_t)8388608;              // 32,768 f32

  k0_prep<<<dim3(4, 65), 256, 0, stream>>>(x, ip_w, ip_b, in_proj_w, h_T, w_p);
  k1_u<<<dim3(16, 64), 256, 0, stream>>>(h_T, w_p, conv_w, conv_b, u);
  k3_delta<<<1000, 256, 0, stream>>>(u, x_proj_w, dt_proj_w, dt_proj_b, delta, du, bm);
  k4_scan<<<dim3(16, 64), 256, 0, stream>>>(delta, du, bm, A_log, state);
  k5_head<<<64, 256, 0, stream>>>(x, ip_w, ip_b, in_proj_w, x_proj_w, u, state,
                                  D_skip, out_proj_w, fc1_w, fc1_b, fc2_w, fc2_b, out);
}

// Round 9
// 311.992 us; speedup vs baseline: 1.2150x; 1.2141x over previous
//
#include <hip/hip_runtime.h>
#include <cstddef>

#define T_LEN 1000
#define B_SZ 64
#define C_IN_ 12
#define D_MODEL_ 128
#define D_INNER_ 256
#define D_STATE_ 16
#define DT_RANK_ 8
#define N_CLS 5

typedef __attribute__((ext_vector_type(8))) short bf16x8;
typedef __attribute__((ext_vector_type(8))) unsigned short u16x8;
typedef __attribute__((ext_vector_type(4))) float f32x4;

__device__ __forceinline__ float sigmoid_f(float x) {
  if (x >= 0.f) return 1.f / (1.f + expf(-x));
  float e = expf(x);
  return e / (1.f + e);
}
__device__ __forceinline__ float softplus_f(float x) {
  return (x > 0.f) ? (x + log1pf(expf(-x))) : log1pf(expf(x));
}
__device__ __forceinline__ unsigned short f2bf(float f) {
  unsigned u = __builtin_bit_cast(unsigned, f);
  u = u + 0x7FFFu + ((u >> 16) & 1u);   // RNE
  return (unsigned short)(u >> 16);
}
__device__ __forceinline__ float bf2f(unsigned short h) {
  unsigned u = ((unsigned)h) << 16;
  return __builtin_bit_cast(float, u);
}

// ---------------------------------------------------------------------------
// Packed fragment layout contract (k0 -> k1):
//  h_pk: per (b, tt) a 4 KB chunk at byte ((b*64+tt)*4096). Within chunk:
//    byte = kt*1024 + lg*256 + lp*16 + j*2  holds bf16 h[t= tt*16+lp][k= kt*32+lg*8+j]
//  => an MFMA A-frag for (tt,kt) is the contiguous 1 KB at kt*1024, lane l
//     reading 16 B at l*16 (row tt*16+(l&15), k kt*32+(l>>4)*8+j).
//  w_pk: same form per n-tile: byte = nt*4096 + kt*1024 + lg*256 + lp*16 + j*2
//     holds bf16 W1[n= nt*16+lp][k= kt*32+lg*8+j]  (B-frag: col n, same k map).
//  A and B use the SAME k enumeration, so any HW within-group k-permutation
//  cancels in the dot product; C/D map is the m89-verified one.
// ---------------------------------------------------------------------------

// K0: h = x@ip_w.T + ip_b  (bf16, frag-packed, zero-filled t>=1000)  +  W pack.
__global__ __launch_bounds__(256) void k0_prep(
    const float* __restrict__ x, const float* __restrict__ ip_w,
    const float* __restrict__ ip_b, const float* __restrict__ in_proj_w,
    char* __restrict__ h_pk, char* __restrict__ w_pk)
{
  __shared__ unsigned short pk_s[8192];      // 16 KB (h block)
  __shared__ unsigned short pkw_s[32768];    // 64 KB (W block) -- only one used
  const int tid = threadIdx.x;

  if (blockIdx.x == 16) {                    // W-pack block
    if (blockIdx.y != 0) return;
    const int n = tid;
    for (int k = 0; k < D_MODEL_; ++k) {
      unsigned short v = f2bf(in_proj_w[(size_t)n * D_MODEL_ + k]);
      int off = ((n >> 4) * 4 + (k >> 5)) * 512 + ((k & 31) >> 3) * 128
              + (n & 15) * 8 + (k & 7);
      pkw_s[off] = v;
    }
    __syncthreads();
    const float4* s4 = (const float4*)pkw_s;
    float4* dst = (float4*)w_pk;
#pragma unroll
    for (int q = 0; q < 16; ++q) dst[tid * 16 + q] = s4[tid * 16 + q];
    return;
  }

  const int tile4 = blockIdx.x;              // 0..15 -> rows tile4*64..+63
  const int b = blockIdx.y;
  const int rl = tid & 63;                   // local row
  const int kc = (tid >> 6) * 32;            // k chunk
  const int t = tile4 * 64 + rl;

  float xr[C_IN_] = {0.f, 0.f, 0.f, 0.f, 0.f, 0.f, 0.f, 0.f, 0.f, 0.f, 0.f, 0.f};
  const bool valid = (t < T_LEN);
  if (valid) {
    const float4* xp = (const float4*)(x + ((size_t)b * T_LEN + t) * C_IN_);
    float4 v0 = xp[0], v1 = xp[1], v2 = xp[2];
    xr[0] = v0.x; xr[1] = v0.y; xr[2] = v0.z;  xr[3] = v0.w;
    xr[4] = v1.x; xr[5] = v1.y; xr[6] = v1.z;  xr[7] = v1.w;
    xr[8] = v2.x; xr[9] = v2.y; xr[10] = v2.z; xr[11] = v2.w;
  }
  for (int kk = 0; kk < 32; ++kk) {
    const int k = kc + kk;
    unsigned short v = 0;
    if (valid) {
      float acc = ip_b[k];
      const float* wr = ip_w + k * C_IN_;
#pragma unroll
      for (int c = 0; c < C_IN_; ++c) acc += xr[c] * wr[c];
      v = f2bf(acc);
    }
    int off = (rl >> 4) * 2048 + (k >> 5) * 512 + ((k & 31) >> 3) * 128
            + (rl & 15) * 8 + (k & 7);
    pk_s[off] = v;
  }
  __syncthreads();
  const float4* s4 = (const float4*)pk_s;
  float4* dst = (float4*)(h_pk + (size_t)(b * 64 + tile4 * 4) * 4096);
#pragma unroll
  for (int q = 0; q < 4; ++q) dst[tid * 4 + q] = s4[tid * 4 + q];
}

// K1 v8: MFMA bf16 GEMM (xm = h @ W1.T) + 3 halo rows (vector path) + causal
// conv + silu -> u (fp32). 4 waves, wave = 16 t-rows x 256 cols. LDS: xm only.
__global__ __launch_bounds__(256) void k1_u(
    const char* __restrict__ h_pk, const char* __restrict__ w_pk,
    const float* __restrict__ conv_w, const float* __restrict__ conv_b,
    float* __restrict__ u_out)
{
  __shared__ float xm[67][260];   // row m = t0-3+m ; stride 260 -> 2-way alias only

  const int tile = blockIdx.x;    // 0..15, t0 = tile*64
  const int b    = blockIdx.y;
  const int t0   = tile * 64;
  const int tid  = threadIdx.x;
  const int w    = tid >> 6;      // wave 0..3
  const int l    = tid & 63;      // lane

  // --- MFMA phase: wave w computes rows tt = tile*4+w (16 rows) x 256 cols ---
  {
    const char* achunk = h_pk + (size_t)(b * 64 + tile * 4 + w) * 4096;
    bf16x8 a0 = *(const bf16x8*)(achunk + 0 * 1024 + l * 16);
    bf16x8 a1 = *(const bf16x8*)(achunk + 1 * 1024 + l * 16);
    bf16x8 a2 = *(const bf16x8*)(achunk + 2 * 1024 + l * 16);
    bf16x8 a3 = *(const bf16x8*)(achunk + 3 * 1024 + l * 16);

    const int row_l = w * 16 + (l >> 4) * 4;   // +r, local t-row of reg r
#pragma unroll
    for (int nt = 0; nt < 16; ++nt) {
      const char* wb = w_pk + (size_t)nt * 4096 + l * 16;
      bf16x8 b0 = *(const bf16x8*)(wb + 0 * 1024);
      bf16x8 b1 = *(const bf16x8*)(wb + 1 * 1024);
      bf16x8 b2 = *(const bf16x8*)(wb + 2 * 1024);
      bf16x8 b3 = *(const bf16x8*)(wb + 3 * 1024);
      f32x4 acc = {0.f, 0.f, 0.f, 0.f};
      acc = __builtin_amdgcn_mfma_f32_16x16x32_bf16(a0, b0, acc, 0, 0, 0);
      acc = __builtin_amdgcn_mfma_f32_16x16x32_bf16(a1, b1, acc, 0, 0, 0);
      acc = __builtin_amdgcn_mfma_f32_16x16x32_bf16(a2, b2, acc, 0, 0, 0);
      acc = __builtin_amdgcn_mfma_f32_16x16x32_bf16(a3, b3, acc, 0, 0, 0);
      const int col = nt * 16 + (l & 15);
#pragma unroll
      for (int r = 0; r < 4; ++r)           // D: row=(l>>4)*4+r, col=l&15 [m89]
        xm[3 + row_l + r][col] = acc[r];
    }
  }

  // --- halo rows t0-3..t0-1 (vector bf16 dot, thread = column n) ---
  {
    const int n = tid;
    float hac[3] = {0.f, 0.f, 0.f};
    if (tile > 0) {
      const char* wrow = w_pk + (size_t)(n >> 4) * 4096 + (n & 15) * 16;
#pragma unroll
      for (int kt = 0; kt < 4; ++kt)
#pragma unroll
        for (int lg = 0; lg < 4; ++lg) {
          u16x8 wv = *(const u16x8*)(wrow + kt * 1024 + lg * 256);
#pragma unroll
          for (int r = 0; r < 3; ++r) {
            const int t = t0 - 3 + r;
            const char* hc = h_pk + (size_t)(b * 64 + (t >> 4)) * 4096;
            u16x8 hv = *(const u16x8*)(hc + kt * 1024 + lg * 256 + (t & 15) * 16);
#pragma unroll
            for (int j = 0; j < 8; ++j) hac[r] += bf2f(hv[j]) * bf2f(wv[j]);
          }
        }
    }
#pragma unroll
    for (int r = 0; r < 3; ++r) xm[r][n] = hac[r];
  }
  __syncthreads();

  // --- conv + silu + store u ---
  {
    const int n = tid;
    const float4 cw = *(const float4*)&conv_w[n * 4];
    const float  cb = conv_b[n];
    float x0 = xm[0][n], x1 = xm[1][n], x2 = xm[2][n];
    for (int i = 0; i < 64; ++i) {
      const int t = t0 + i;
      float x3 = xm[3 + i][n];
      if (t < T_LEN) {
        float s = cb + x0 * cw.x + x1 * cw.y + x2 * cw.z + x3 * cw.w;
        u_out[(((size_t)b * T_LEN + t) << 8) + n] = s * sigmoid_f(s);
      }
      x0 = x1; x1 = x2; x2 = x3;
    }
  }
}

// K3 v6: phase1 dbc = u @ xp[0:24].T; phase2 thread-per-n; delta/du/bm in BF16
// (scan-only consumers -- precision irrelevant there), coalesced [t][d].
__global__ __launch_bounds__(256) void k3_delta(
    const float* __restrict__ u, const float* __restrict__ x_proj_w,
    const float* __restrict__ dt_proj_w, const float* __restrict__ dt_proj_b,
    unsigned short* __restrict__ delta_bf, unsigned short* __restrict__ du_bf,
    unsigned short* __restrict__ bm_bf)
{
  __shared__ float4 xp4[24][65];
  __shared__ float dt_s[64][9];

  const int row0 = blockIdx.x * 64;   // 1000 blocks
  const int tid = threadIdx.x;

  for (int f = tid; f < 24 * 64; f += 256) {
    int c = f >> 6, k4 = f & 63;
    xp4[c][k4] = *(const float4*)&x_proj_w[(size_t)c * 256 + k4 * 4];
  }
  const float4 w0 = *(const float4*)&dt_proj_w[(size_t)tid * 8];
  const float4 w1 = *(const float4*)&dt_proj_w[(size_t)tid * 8 + 4];
  const float bias = dt_proj_b[tid];
  __syncthreads();

  // phase 1
  {
    const int r2 = tid >> 3, cg = tid & 7;
    const int ra = 2 * r2;
    const float4* ua4 = (const float4*)(u + (size_t)(row0 + ra) * 256);
    const float4* ub4 = (const float4*)(u + (size_t)(row0 + ra + 1) * 256);
    float a0 = 0.f, a1 = 0.f, a2 = 0.f, b0 = 0.f, b1 = 0.f, b2 = 0.f;
    for (int k4 = 0; k4 < 64; ++k4) {
      float4 a = ua4[k4], bb = ub4[k4];
      float4 q0 = xp4[cg * 3 + 0][k4];
      float4 q1 = xp4[cg * 3 + 1][k4];
      float4 q2 = xp4[cg * 3 + 2][k4];
      a0 += a.x * q0.x + a.y * q0.y + a.z * q0.z + a.w * q0.w;
      a1 += a.x * q1.x + a.y * q1.y + a.z * q1.z + a.w * q1.w;
      a2 += a.x * q2.x + a.y * q2.y + a.z * q2.z + a.w * q2.w;
      b0 += bb.x * q0.x + bb.y * q0.y + bb.z * q0.z + bb.w * q0.w;
      b1 += bb.x * q1.x + bb.y * q1.y + bb.z * q1.z + bb.w * q1.w;
      b2 += bb.x * q2.x + bb.y * q2.y + bb.z * q2.z + bb.w * q2.w;
    }
    float va[2][3] = {{a0, a1, a2}, {b0, b1, b2}};
#pragma unroll
    for (int rr = 0; rr < 2; ++rr)
#pragma unroll
      for (int c = 0; c < 3; ++c) {
        int col = cg * 3 + c;
        int row = ra + rr;
        if (col < 8) dt_s[row][col] = va[rr][c];
        else bm_bf[((size_t)(row0 + row)) * 16 + (col - 8)] = f2bf(va[rr][c]);
      }
  }
  __syncthreads();

  // phase 2
  for (int r = 0; r < 64; ++r) {
    float pre = bias
      + dt_s[r][0] * w0.x + dt_s[r][1] * w0.y + dt_s[r][2] * w0.z + dt_s[r][3] * w0.w
      + dt_s[r][4] * w1.x + dt_s[r][5] * w1.y + dt_s[r][6] * w1.z + dt_s[r][7] * w1.w;
    float dlt = softplus_f(pre);
    size_t o = (size_t)(row0 + r) * 256 + tid;
    delta_bf[o] = f2bf(dlt);
    du_bf[o] = f2bf(dlt * u[o]);
  }
}

// K4 v7: bf16 inputs (half traffic). thread = (b,d,n); broadcast b16 reads.
__global__ __launch_bounds__(256) void k4_scan(
    const unsigned short* __restrict__ delta_bf,
    const unsigned short* __restrict__ du_bf,
    const unsigned short* __restrict__ bm_bf,
    const float* __restrict__ A_log, float* __restrict__ state_out)
{
  const int d0 = blockIdx.x * 16;
  const int b  = blockIdx.y;
  const int tid = threadIdx.x;
  const int dl = tid >> 4;
  const int n  = tid & 15;
  const int d  = d0 + dl;

  const float A2 = -expf(A_log[(size_t)d * 16 + n]) * 1.4426950408889634f;
  float s = 0.f;

  const unsigned short* dp = delta_bf + (size_t)b * T_LEN * 256 + d;
  const unsigned short* xp = du_bf    + (size_t)b * T_LEN * 256 + d;
  const unsigned short* bp = bm_bf    + (size_t)b * T_LEN * 16 + n;

#pragma unroll 2
  for (int t = 0; t < T_LEN; t += 4) {
    float dv0 = bf2f(dp[(t + 0) * 256]);
    float dv1 = bf2f(dp[(t + 1) * 256]);
    float dv2 = bf2f(dp[(t + 2) * 256]);
    float dv3 = bf2f(dp[(t + 3) * 256]);
    float xv0 = bf2f(xp[(t + 0) * 256]);
    float xv1 = bf2f(xp[(t + 1) * 256]);
    float xv2 = bf2f(xp[(t + 2) * 256]);
    float xv3 = bf2f(xp[(t + 3) * 256]);
    float bv0 = bf2f(bp[(t + 0) * 16]);
    float bv1 = bf2f(bp[(t + 1) * 16]);
    float bv2 = bf2f(bp[(t + 2) * 16]);
    float bv3 = bf2f(bp[(t + 3) * 16]);
    s = exp2f(dv0 * A2) * s + xv0 * bv0;
    s = exp2f(dv1 * A2) * s + xv1 * bv1;
    s = exp2f(dv2 * A2) * s + xv2 * bv2;
    s = exp2f(dv3 * A2) * s + xv3 * bv3;
  }
  state_out[((size_t)b * 256 + d) * 16 + n] = s;
}

// K5: per-batch head (float4 weight reads).
__global__ __launch_bounds__(256) void k5_head(
    const float* __restrict__ x, const float* __restrict__ ip_w,
    const float* __restrict__ ip_b, const float* __restrict__ in_proj_w,
    const float* __restrict__ x_proj_w, const float* __restrict__ u,
    const float* __restrict__ state, const float* __restrict__ D_skip,
    const float* __restrict__ out_proj_w, const float* __restrict__ fc1_w,
    const float* __restrict__ fc1_b, const float* __restrict__ fc2_w,
    const float* __restrict__ fc2_b, float* __restrict__ out)
{
  const int b = blockIdx.x, tid = threadIdx.x;
  __shared__ float hl[128], ul[256], zs[256], cm[16], yv[256], ov[128], hid[64];
  if (tid < 128) {
    float acc = ip_b[tid];
    const float* xr = x + ((size_t)b * T_LEN + (T_LEN - 1)) * C_IN_;
#pragma unroll
    for (int c = 0; c < C_IN_; ++c) acc += xr[c] * ip_w[tid * C_IN_ + c];
    hl[tid] = acc;
  }
  ul[tid] = u[((size_t)b * T_LEN + (T_LEN - 1)) * 256 + tid];
  __syncthreads();
  {
    float acc = 0.f;
    const float4* wv = (const float4*)(in_proj_w + (size_t)(256 + tid) * 128);
    const float4* h4 = (const float4*)hl;
    for (int k = 0; k < 32; ++k) {
      float4 a = wv[k], c = h4[k];
      acc += c.x * a.x + c.y * a.y + c.z * a.z + c.w * a.w;
    }
    zs[tid] = acc * sigmoid_f(acc);
  }
  if (tid < 16) {
    float acc = 0.f;
    const float4* wv = (const float4*)(x_proj_w + (size_t)(24 + tid) * 256);
    const float4* u4 = (const float4*)ul;
    for (int k = 0; k < 64; ++k) {
      float4 a = wv[k], c = u4[k];
      acc += c.x * a.x + c.y * a.y + c.z * a.z + c.w * a.w;
    }
    cm[tid] = acc;
  }
  __syncthreads();
  {
    const float* st = state + ((size_t)b * 256 + tid) * 16;
    float acc = 0.f;
#pragma unroll
    for (int n = 0; n < 16; ++n) acc += st[n] * cm[n];
    yv[tid] = (acc + ul[tid] * D_skip[tid]) * zs[tid];
  }
  __syncthreads();
  if (tid < 128) {
    float acc = 0.f;
    const float4* wv = (const float4*)(out_proj_w + (size_t)tid * 256);
    const float4* y4 = (const float4*)yv;
    for (int k = 0; k < 64; ++k) {
      float4 a = wv[k], c = y4[k];
      acc += c.x * a.x + c.y * a.y + c.z * a.z + c.w * a.w;
    }
    ov[tid] = acc;
  }
  __syncthreads();
  if (tid < 64) {
    float acc = fc1_b[tid];
    const float4* wv = (const float4*)(fc1_w + (size_t)tid * 128);
    const float4* o4 = (const float4*)ov;
    for (int k = 0; k < 32; ++k) {
      float4 a = wv[k], c = o4[k];
      acc += c.x * a.x + c.y * a.y + c.z * a.z + c.w * a.w;
    }
    hid[tid] = fmaxf(acc, 0.f);
  }
  __syncthreads();
  if (tid < N_CLS) {
    float acc = fc2_b[tid];
    const float* wv = fc2_w + (size_t)tid * 64;
    for (int k = 0; k < 64; ++k) acc += hid[k] * wv[k];
    out[b * N_CLS + tid] = acc;
  }
}

extern "C" void kernel_launch(void* const* d_in, const int* in_sizes, int n_in,
                              void* d_out, int out_size, void* d_ws, size_t ws_size,
                              hipStream_t stream) {
  (void)in_sizes; (void)n_in; (void)out_size; (void)ws_size;
  const float* x         = (const float*)d_in[0];
  const float* ip_w      = (const float*)d_in[1];
  const float* ip_b      = (const float*)d_in[2];
  const float* in_proj_w = (const float*)d_in[3];
  const float* conv_w    = (const float*)d_in[4];
  const float* conv_b    = (const float*)d_in[5];
  const float* x_proj_w  = (const float*)d_in[6];
  const float* dt_proj_w = (const float*)d_in[7];
  const float* dt_proj_b = (const float*)d_in[8];
  const float* A_log     = (const float*)d_in[9];
  const float* D_skip    = (const float*)d_in[10];
  const float* out_proj_w= (const float*)d_in[11];
  const float* fc1_w     = (const float*)d_in[12];
  const float* fc1_b     = (const float*)d_in[13];
  const float* fc2_w     = (const float*)d_in[14];
  const float* fc2_b     = (const float*)d_in[15];
  float* out = (float*)d_out;

  float* u              = (float*)d_ws;                         // 65.5 MB
  unsigned short* delta = (unsigned short*)(u + (size_t)16384000);   // 32.8 MB
  unsigned short* du    = delta + (size_t)16384000;             // 32.8 MB
  unsigned short* bm    = du + (size_t)16384000;                // 2.0 MB
  float* state          = (float*)(bm + (size_t)1024000);       // 1.0 MB
  char* h_pk            = (char*)(state + (size_t)262144);      // 16.8 MB
  char* w_pk            = h_pk + (size_t)64 * 64 * 4096;        // 64 KB

  k0_prep<<<dim3(17, 64), 256, 0, stream>>>(x, ip_w, ip_b, in_proj_w, h_pk, w_pk);
  k1_u<<<dim3(16, 64), 256, 0, stream>>>(h_pk, w_pk, conv_w, conv_b, u);
  k3_delta<<<1000, 256, 0, stream>>>(u, x_proj_w, dt_proj_w, dt_proj_b, delta, du, bm);
  k4_scan<<<dim3(16, 64), 256, 0, stream>>>(delta, du, bm, A_log, state);
  k5_head<<<64, 256, 0, stream>>>(x, ip_w, ip_b, in_proj_w, x_proj_w, u, state,
                                  D_skip, out_proj_w, fc1_w, fc1_b, fc2_w, fc2_b, out);
}

// Round 10
// 288.417 us; speedup vs baseline: 1.3143x; 1.0817x over previous
//
#include <hip/hip_runtime.h>
#include <cstddef>

#define T_LEN 1000
#define B_SZ 64
#define C_IN_ 12
#define D_MODEL_ 128
#define D_INNER_ 256
#define D_STATE_ 16
#define DT_RANK_ 8
#define N_CLS 5

typedef __attribute__((ext_vector_type(8))) short bf16x8;
typedef __attribute__((ext_vector_type(8))) unsigned short u16x8;
typedef __attribute__((ext_vector_type(4))) float f32x4;

__device__ __forceinline__ float sigmoid_f(float x) {
  if (x >= 0.f) return 1.f / (1.f + expf(-x));
  float e = expf(x);
  return e / (1.f + e);
}
__device__ __forceinline__ float softplus_f(float x) {
  return (x > 0.f) ? (x + log1pf(expf(-x))) : log1pf(expf(x));
}
__device__ __forceinline__ unsigned short f2bf(float f) {
  unsigned u = __builtin_bit_cast(unsigned, f);
  u = u + 0x7FFFu + ((u >> 16) & 1u);   // RNE
  return (unsigned short)(u >> 16);
}
__device__ __forceinline__ float bf2f(unsigned short h) {
  unsigned u = ((unsigned)h) << 16;
  return __builtin_bit_cast(float, u);
}

// K0: h = x@ip_w.T + ip_b (bf16, MFMA-frag-packed, zero-filled t>=1000) + W pack.
__global__ __launch_bounds__(256) void k0_prep(
    const float* __restrict__ x, const float* __restrict__ ip_w,
    const float* __restrict__ ip_b, const float* __restrict__ in_proj_w,
    char* __restrict__ h_pk, char* __restrict__ w_pk)
{
  __shared__ unsigned short pk_s[8192];      // 16 KB (h block)
  __shared__ unsigned short pkw_s[32768];    // 64 KB (W block)
  const int tid = threadIdx.x;

  if (blockIdx.x == 16) {                    // W-pack block
    if (blockIdx.y != 0) return;
    const int n = tid;
    for (int k = 0; k < D_MODEL_; ++k) {
      unsigned short v = f2bf(in_proj_w[(size_t)n * D_MODEL_ + k]);
      int off = ((n >> 4) * 4 + (k >> 5)) * 512 + ((k & 31) >> 3) * 128
              + (n & 15) * 8 + (k & 7);
      pkw_s[off] = v;
    }
    __syncthreads();
    const float4* s4 = (const float4*)pkw_s;
    float4* dst = (float4*)w_pk;
#pragma unroll
    for (int q = 0; q < 16; ++q) dst[tid * 16 + q] = s4[tid * 16 + q];
    return;
  }

  const int tile4 = blockIdx.x;              // 0..15
  const int b = blockIdx.y;
  const int rl = tid & 63;
  const int kc = (tid >> 6) * 32;
  const int t = tile4 * 64 + rl;

  float xr[C_IN_] = {0.f, 0.f, 0.f, 0.f, 0.f, 0.f, 0.f, 0.f, 0.f, 0.f, 0.f, 0.f};
  const bool valid = (t < T_LEN);
  if (valid) {
    const float4* xp = (const float4*)(x + ((size_t)b * T_LEN + t) * C_IN_);
    float4 v0 = xp[0], v1 = xp[1], v2 = xp[2];
    xr[0] = v0.x; xr[1] = v0.y; xr[2] = v0.z;  xr[3] = v0.w;
    xr[4] = v1.x; xr[5] = v1.y; xr[6] = v1.z;  xr[7] = v1.w;
    xr[8] = v2.x; xr[9] = v2.y; xr[10] = v2.z; xr[11] = v2.w;
  }
  for (int kk = 0; kk < 32; ++kk) {
    const int k = kc + kk;
    unsigned short v = 0;
    if (valid) {
      float acc = ip_b[k];
      const float* wr = ip_w + k * C_IN_;
#pragma unroll
      for (int c = 0; c < C_IN_; ++c) acc += xr[c] * wr[c];
      v = f2bf(acc);
    }
    int off = (rl >> 4) * 2048 + (k >> 5) * 512 + ((k & 31) >> 3) * 128
            + (rl & 15) * 8 + (k & 7);
    pk_s[off] = v;
  }
  __syncthreads();
  const float4* s4 = (const float4*)pk_s;
  float4* dst = (float4*)(h_pk + (size_t)(b * 64 + tile4 * 4) * 4096);
#pragma unroll
  for (int q = 0; q < 4; ++q) dst[tid * 4 + q] = s4[tid * 4 + q];
}

// K1 v8 (unchanged): MFMA bf16 GEMM + halo + causal conv + silu -> u (fp32).
__global__ __launch_bounds__(256) void k1_u(
    const char* __restrict__ h_pk, const char* __restrict__ w_pk,
    const float* __restrict__ conv_w, const float* __restrict__ conv_b,
    float* __restrict__ u_out)
{
  __shared__ float xm[67][260];

  const int tile = blockIdx.x;
  const int b    = blockIdx.y;
  const int t0   = tile * 64;
  const int tid  = threadIdx.x;
  const int w    = tid >> 6;
  const int l    = tid & 63;

  {
    const char* achunk = h_pk + (size_t)(b * 64 + tile * 4 + w) * 4096;
    bf16x8 a0 = *(const bf16x8*)(achunk + 0 * 1024 + l * 16);
    bf16x8 a1 = *(const bf16x8*)(achunk + 1 * 1024 + l * 16);
    bf16x8 a2 = *(const bf16x8*)(achunk + 2 * 1024 + l * 16);
    bf16x8 a3 = *(const bf16x8*)(achunk + 3 * 1024 + l * 16);

    const int row_l = w * 16 + (l >> 4) * 4;
#pragma unroll
    for (int nt = 0; nt < 16; ++nt) {
      const char* wb = w_pk + (size_t)nt * 4096 + l * 16;
      bf16x8 b0 = *(const bf16x8*)(wb + 0 * 1024);
      bf16x8 b1 = *(const bf16x8*)(wb + 1 * 1024);
      bf16x8 b2 = *(const bf16x8*)(wb + 2 * 1024);
      bf16x8 b3 = *(const bf16x8*)(wb + 3 * 1024);
      f32x4 acc = {0.f, 0.f, 0.f, 0.f};
      acc = __builtin_amdgcn_mfma_f32_16x16x32_bf16(a0, b0, acc, 0, 0, 0);
      acc = __builtin_amdgcn_mfma_f32_16x16x32_bf16(a1, b1, acc, 0, 0, 0);
      acc = __builtin_amdgcn_mfma_f32_16x16x32_bf16(a2, b2, acc, 0, 0, 0);
      acc = __builtin_amdgcn_mfma_f32_16x16x32_bf16(a3, b3, acc, 0, 0, 0);
      const int col = nt * 16 + (l & 15);
#pragma unroll
      for (int r = 0; r < 4; ++r)
        xm[3 + row_l + r][col] = acc[r];
    }
  }

  {
    const int n = tid;
    float hac[3] = {0.f, 0.f, 0.f};
    if (tile > 0) {
      const char* wrow = w_pk + (size_t)(n >> 4) * 4096 + (n & 15) * 16;
#pragma unroll
      for (int kt = 0; kt < 4; ++kt)
#pragma unroll
        for (int lg = 0; lg < 4; ++lg) {
          u16x8 wv = *(const u16x8*)(wrow + kt * 1024 + lg * 256);
#pragma unroll
          for (int r = 0; r < 3; ++r) {
            const int t = t0 - 3 + r;
            const char* hc = h_pk + (size_t)(b * 64 + (t >> 4)) * 4096;
            u16x8 hv = *(const u16x8*)(hc + kt * 1024 + lg * 256 + (t & 15) * 16);
#pragma unroll
            for (int j = 0; j < 8; ++j) hac[r] += bf2f(hv[j]) * bf2f(wv[j]);
          }
        }
    }
#pragma unroll
    for (int r = 0; r < 3; ++r) xm[r][n] = hac[r];
  }
  __syncthreads();

  {
    const int n = tid;
    const float4 cw = *(const float4*)&conv_w[n * 4];
    const float  cb = conv_b[n];
    float x0 = xm[0][n], x1 = xm[1][n], x2 = xm[2][n];
    for (int i = 0; i < 64; ++i) {
      const int t = t0 + i;
      float x3 = xm[3 + i][n];
      if (t < T_LEN) {
        float s = cb + x0 * cw.x + x1 * cw.y + x2 * cw.z + x3 * cw.w;
        u_out[(((size_t)b * T_LEN + t) << 8) + n] = s * sigmoid_f(s);
      }
      x0 = x1; x1 = x2; x2 = x3;
    }
  }
}

// K3 v7: phase1 dbc = u @ xp[0:24].T (bm -> LDS); phase2 thread-per-d emits
// delta/du TIME-PACKED bf16: pk[b][t8][d][8] (one b128 store per 8 t).
// bm packed likewise as pk_bm[b][t8][n][8]. 1000 ≡ 0 mod 8 keeps groups aligned.
__global__ __launch_bounds__(256) void k3_delta(
    const float* __restrict__ u, const float* __restrict__ x_proj_w,
    const float* __restrict__ dt_proj_w, const float* __restrict__ dt_proj_b,
    unsigned short* __restrict__ pk_delta, unsigned short* __restrict__ pk_du,
    unsigned short* __restrict__ pk_bm)
{
  __shared__ float4 xp4[24][65];
  __shared__ float dt_s[64][9];
  __shared__ float bm_s[64][17];

  const int row0 = blockIdx.x * 64;   // 1000 blocks
  const int tid = threadIdx.x;

  for (int f = tid; f < 24 * 64; f += 256) {
    int c = f >> 6, k4 = f & 63;
    xp4[c][k4] = *(const float4*)&x_proj_w[(size_t)c * 256 + k4 * 4];
  }
  const float4 w0 = *(const float4*)&dt_proj_w[(size_t)tid * 8];
  const float4 w1 = *(const float4*)&dt_proj_w[(size_t)tid * 8 + 4];
  const float bias = dt_proj_b[tid];
  __syncthreads();

  // phase 1
  {
    const int r2 = tid >> 3, cg = tid & 7;
    const int ra = 2 * r2;
    const float4* ua4 = (const float4*)(u + (size_t)(row0 + ra) * 256);
    const float4* ub4 = (const float4*)(u + (size_t)(row0 + ra + 1) * 256);
    float a0 = 0.f, a1 = 0.f, a2 = 0.f, b0 = 0.f, b1 = 0.f, b2 = 0.f;
    for (int k4 = 0; k4 < 64; ++k4) {
      float4 a = ua4[k4], bb = ub4[k4];
      float4 q0 = xp4[cg * 3 + 0][k4];
      float4 q1 = xp4[cg * 3 + 1][k4];
      float4 q2 = xp4[cg * 3 + 2][k4];
      a0 += a.x * q0.x + a.y * q0.y + a.z * q0.z + a.w * q0.w;
      a1 += a.x * q1.x + a.y * q1.y + a.z * q1.z + a.w * q1.w;
      a2 += a.x * q2.x + a.y * q2.y + a.z * q2.z + a.w * q2.w;
      b0 += bb.x * q0.x + bb.y * q0.y + bb.z * q0.z + bb.w * q0.w;
      b1 += bb.x * q1.x + bb.y * q1.y + bb.z * q1.z + bb.w * q1.w;
      b2 += bb.x * q2.x + bb.y * q2.y + bb.z * q2.z + bb.w * q2.w;
    }
    float va[2][3] = {{a0, a1, a2}, {b0, b1, b2}};
#pragma unroll
    for (int rr = 0; rr < 2; ++rr)
#pragma unroll
      for (int c = 0; c < 3; ++c) {
        int col = cg * 3 + c;
        int row = ra + rr;
        if (col < 8) dt_s[row][col] = va[rr][c];
        else bm_s[row][col - 8] = va[rr][c];
      }
  }
  __syncthreads();

  // phase 2: thread = d; 8 groups of 8 t -> one b128 store per array per group
  for (int g = 0; g < 8; ++g) {
    unsigned short pd[8], pu[8];
#pragma unroll
    for (int j = 0; j < 8; ++j) {
      int r = g * 8 + j;
      float pre = bias
        + dt_s[r][0] * w0.x + dt_s[r][1] * w0.y + dt_s[r][2] * w0.z + dt_s[r][3] * w0.w
        + dt_s[r][4] * w1.x + dt_s[r][5] * w1.y + dt_s[r][6] * w1.z + dt_s[r][7] * w1.w;
      float dlt = softplus_f(pre);
      size_t o = (size_t)(row0 + r) * 256 + tid;
      pd[j] = f2bf(dlt);
      pu[j] = f2bf(dlt * u[o]);
    }
    int row = row0 + g * 8;
    int bb_ = row / 1000;
    int t   = row - bb_ * 1000;          // multiple of 8
    size_t base = (((size_t)bb_ * 125 + (t >> 3)) * 256 + tid) * 8;
    *(u16x8*)&pk_delta[base] = *(u16x8*)pd;
    *(u16x8*)&pk_du[base]    = *(u16x8*)pu;
  }
  // bm pack: threads 0..15
  if (tid < 16) {
    for (int g = 0; g < 8; ++g) {
      unsigned short pb[8];
#pragma unroll
      for (int j = 0; j < 8; ++j) pb[j] = f2bf(bm_s[g * 8 + j][tid]);
      int row = row0 + g * 8;
      int bb_ = row / 1000;
      int t   = row - bb_ * 1000;
      *(u16x8*)&pk_bm[(((size_t)bb_ * 125 + (t >> 3)) * 16 + tid) * 8] = *(u16x8*)pb;
    }
  }
}

// K4 v8: time-packed reads -- one b128 per operand per 8 steps (24x fewer
// VMEM inst), 16-lane broadcast, zero overfetch. thread = (b, d, n).
__global__ __launch_bounds__(256) void k4_scan(
    const unsigned short* __restrict__ pk_delta,
    const unsigned short* __restrict__ pk_du,
    const unsigned short* __restrict__ pk_bm,
    const float* __restrict__ A_log, float* __restrict__ state_out)
{
  const int d0 = blockIdx.x * 16;
  const int b  = blockIdx.y;
  const int tid = threadIdx.x;
  const int dl = tid >> 4;
  const int n  = tid & 15;
  const int d  = d0 + dl;

  const float A2 = -expf(A_log[(size_t)d * 16 + n]) * 1.4426950408889634f;
  float s = 0.f;

  const unsigned short* dp = pk_delta + ((size_t)b * 125 * 256 + d) * 8;
  const unsigned short* xp = pk_du    + ((size_t)b * 125 * 256 + d) * 8;
  const unsigned short* bp = pk_bm    + ((size_t)b * 125 * 16 + n) * 8;

#pragma unroll 2
  for (int t8 = 0; t8 < 125; ++t8) {
    u16x8 dv = *(const u16x8*)(dp + (size_t)t8 * 2048);
    u16x8 xv = *(const u16x8*)(xp + (size_t)t8 * 2048);
    u16x8 bv = *(const u16x8*)(bp + (size_t)t8 * 128);
#pragma unroll
    for (int j = 0; j < 8; ++j)
      s = exp2f(bf2f(dv[j]) * A2) * s + bf2f(xv[j]) * bf2f(bv[j]);
  }
  state_out[((size_t)b * 256 + d) * 16 + n] = s;
}

// K5: per-batch head (unchanged).
__global__ __launch_bounds__(256) void k5_head(
    const float* __restrict__ x, const float* __restrict__ ip_w,
    const float* __restrict__ ip_b, const float* __restrict__ in_proj_w,
    const float* __restrict__ x_proj_w, const float* __restrict__ u,
    const float* __restrict__ state, const float* __restrict__ D_skip,
    const float* __restrict__ out_proj_w, const float* __restrict__ fc1_w,
    const float* __restrict__ fc1_b, const float* __restrict__ fc2_w,
    const float* __restrict__ fc2_b, float* __restrict__ out)
{
  const int b = blockIdx.x, tid = threadIdx.x;
  __shared__ float hl[128], ul[256], zs[256], cm[16], yv[256], ov[128], hid[64];
  if (tid < 128) {
    float acc = ip_b[tid];
    const float* xr = x + ((size_t)b * T_LEN + (T_LEN - 1)) * C_IN_;
#pragma unroll
    for (int c = 0; c < C_IN_; ++c) acc += xr[c] * ip_w[tid * C_IN_ + c];
    hl[tid] = acc;
  }
  ul[tid] = u[((size_t)b * T_LEN + (T_LEN - 1)) * 256 + tid];
  __syncthreads();
  {
    float acc = 0.f;
    const float4* wv = (const float4*)(in_proj_w + (size_t)(256 + tid) * 128);
    const float4* h4 = (const float4*)hl;
    for (int k = 0; k < 32; ++k) {
      float4 a = wv[k], c = h4[k];
      acc += c.x * a.x + c.y * a.y + c.z * a.z + c.w * a.w;
    }
    zs[tid] = acc * sigmoid_f(acc);
  }
  if (tid < 16) {
    float acc = 0.f;
    const float4* wv = (const float4*)(x_proj_w + (size_t)(24 + tid) * 256);
    const float4* u4 = (const float4*)ul;
    for (int k = 0; k < 64; ++k) {
      float4 a = wv[k], c = u4[k];
      acc += c.x * a.x + c.y * a.y + c.z * a.z + c.w * a.w;
    }
    cm[tid] = acc;
  }
  __syncthreads();
  {
    const float* st = state + ((size_t)b * 256 + tid) * 16;
    float acc = 0.f;
#pragma unroll
    for (int n = 0; n < 16; ++n) acc += st[n] * cm[n];
    yv[tid] = (acc + ul[tid] * D_skip[tid]) * zs[tid];
  }
  __syncthreads();
  if (tid < 128) {
    float acc = 0.f;
    const float4* wv = (const float4*)(out_proj_w + (size_t)tid * 256);
    const float4* y4 = (const float4*)yv;
    for (int k = 0; k < 64; ++k) {
      float4 a = wv[k], c = y4[k];
      acc += c.x * a.x + c.y * a.y + c.z * a.z + c.w * a.w;
    }
    ov[tid] = acc;
  }
  __syncthreads();
  if (tid < 64) {
    float acc = fc1_b[tid];
    const float4* wv = (const float4*)(fc1_w + (size_t)tid * 128);
    const float4* o4 = (const float4*)ov;
    for (int k = 0; k < 32; ++k) {
      float4 a = wv[k], c = o4[k];
      acc += c.x * a.x + c.y * a.y + c.z * a.z + c.w * a.w;
    }
    hid[tid] = fmaxf(acc, 0.f);
  }
  __syncthreads();
  if (tid < N_CLS) {
    float acc = fc2_b[tid];
    const float* wv = fc2_w + (size_t)tid * 64;
    for (int k = 0; k < 64; ++k) acc += hid[k] * wv[k];
    out[b * N_CLS + tid] = acc;
  }
}

extern "C" void kernel_launch(void* const* d_in, const int* in_sizes, int n_in,
                              void* d_out, int out_size, void* d_ws, size_t ws_size,
                              hipStream_t stream) {
  (void)in_sizes; (void)n_in; (void)out_size; (void)ws_size;
  const float* x         = (const float*)d_in[0];
  const float* ip_w      = (const float*)d_in[1];
  const float* ip_b      = (const float*)d_in[2];
  const float* in_proj_w = (const float*)d_in[3];
  const float* conv_w    = (const float*)d_in[4];
  const float* conv_b    = (const float*)d_in[5];
  const float* x_proj_w  = (const float*)d_in[6];
  const float* dt_proj_w = (const float*)d_in[7];
  const float* dt_proj_b = (const float*)d_in[8];
  const float* A_log     = (const float*)d_in[9];
  const float* D_skip    = (const float*)d_in[10];
  const float* out_proj_w= (const float*)d_in[11];
  const float* fc1_w     = (const float*)d_in[12];
  const float* fc1_b     = (const float*)d_in[13];
  const float* fc2_w     = (const float*)d_in[14];
  const float* fc2_b     = (const float*)d_in[15];
  float* out = (float*)d_out;

  float* u              = (float*)d_ws;                            // 65.5 MB
  unsigned short* delta = (unsigned short*)(u + (size_t)16384000); // 32.8 MB packed
  unsigned short* du    = delta + (size_t)16384000;                // 32.8 MB packed
  unsigned short* bm    = du + (size_t)16384000;                   // 2.0 MB packed
  float* state          = (float*)(bm + (size_t)1024000);          // 1.0 MB
  char* h_pk            = (char*)(state + (size_t)262144);         // 16.8 MB
  char* w_pk            = h_pk + (size_t)64 * 64 * 4096;           // 64 KB

  k0_prep<<<dim3(17, 64), 256, 0, stream>>>(x, ip_w, ip_b, in_proj_w, h_pk, w_pk);
  k1_u<<<dim3(16, 64), 256, 0, stream>>>(h_pk, w_pk, conv_w, conv_b, u);
  k3_delta<<<1000, 256, 0, stream>>>(u, x_proj_w, dt_proj_w, dt_proj_b, delta, du, bm);
  k4_scan<<<dim3(16, 64), 256, 0, stream>>>(delta, du, bm, A_log, state);
  k5_head<<<64, 256, 0, stream>>>(x, ip_w, ip_b, in_proj_w, x_proj_w, u, state,
                                  D_skip, out_proj_w, fc1_w, fc1_b, fc2_w, fc2_b, out);
}

// Round 11
// 209.147 us; speedup vs baseline: 1.8125x; 1.3790x over previous
//
#include <hip/hip_runtime.h>
#include <cstddef>

#define T_LEN 1000
#define B_SZ 64
#define C_IN_ 12
#define D_MODEL_ 128
#define D_INNER_ 256
#define D_STATE_ 16
#define DT_RANK_ 8
#define N_CLS 5

typedef __attribute__((ext_vector_type(8))) short bf16x8;
typedef __attribute__((ext_vector_type(8))) unsigned short u16x8;
typedef __attribute__((ext_vector_type(4))) float f32x4;

__device__ __forceinline__ float fast_exp2(float x) {
#if __has_builtin(__builtin_amdgcn_exp2f)
  return __builtin_amdgcn_exp2f(x);
#else
  float r; asm volatile("v_exp_f32 %0, %1" : "=v"(r) : "v"(x)); return r;
#endif
}
__device__ __forceinline__ float fast_log2(float x) {
#if __has_builtin(__builtin_amdgcn_logf)
  return __builtin_amdgcn_logf(x);
#else
  float r; asm volatile("v_log_f32 %0, %1" : "=v"(r) : "v"(x)); return r;
#endif
}

__device__ __forceinline__ float sigmoid_f(float x) {
  if (x >= 0.f) return 1.f / (1.f + expf(-x));
  float e = expf(x);
  return e / (1.f + e);
}
// softplus via raw v_exp/v_log: |err| ~1e-7, far under the bf16 storage quantum.
__device__ __forceinline__ float softplus_f(float x) {
  const float L = 1.4426950408889634f, iL = 0.6931471805599453f;
  float e = fast_exp2(-fabsf(x) * L);       // e^{-|x|} in (0,1]
  float l = fast_log2(1.f + e) * iL;        // log1p(e^{-|x|})
  return fmaxf(x, 0.f) + l;
}
__device__ __forceinline__ unsigned short f2bf(float f) {
  unsigned u = __builtin_bit_cast(unsigned, f);
  u = u + 0x7FFFu + ((u >> 16) & 1u);   // RNE
  return (unsigned short)(u >> 16);
}
__device__ __forceinline__ float bf2f(unsigned short h) {
  unsigned u = ((unsigned)h) << 16;
  return __builtin_bit_cast(float, u);
}

// K0: h = x@ip_w.T + ip_b (bf16, MFMA-frag-packed, zero-filled t>=1000) + W pack.
__global__ __launch_bounds__(256) void k0_prep(
    const float* __restrict__ x, const float* __restrict__ ip_w,
    const float* __restrict__ ip_b, const float* __restrict__ in_proj_w,
    char* __restrict__ h_pk, char* __restrict__ w_pk)
{
  __shared__ unsigned short pk_s[8192];
  __shared__ unsigned short pkw_s[32768];
  const int tid = threadIdx.x;

  if (blockIdx.x == 16) {                    // W-pack block
    if (blockIdx.y != 0) return;
    const int n = tid;
    for (int k = 0; k < D_MODEL_; ++k) {
      unsigned short v = f2bf(in_proj_w[(size_t)n * D_MODEL_ + k]);
      int off = ((n >> 4) * 4 + (k >> 5)) * 512 + ((k & 31) >> 3) * 128
              + (n & 15) * 8 + (k & 7);
      pkw_s[off] = v;
    }
    __syncthreads();
    const float4* s4 = (const float4*)pkw_s;
    float4* dst = (float4*)w_pk;
#pragma unroll
    for (int q = 0; q < 16; ++q) dst[tid * 16 + q] = s4[tid * 16 + q];
    return;
  }

  const int tile4 = blockIdx.x;
  const int b = blockIdx.y;
  const int rl = tid & 63;
  const int kc = (tid >> 6) * 32;
  const int t = tile4 * 64 + rl;

  float xr[C_IN_] = {0.f, 0.f, 0.f, 0.f, 0.f, 0.f, 0.f, 0.f, 0.f, 0.f, 0.f, 0.f};
  const bool valid = (t < T_LEN);
  if (valid) {
    const float4* xp = (const float4*)(x + ((size_t)b * T_LEN + t) * C_IN_);
    float4 v0 = xp[0], v1 = xp[1], v2 = xp[2];
    xr[0] = v0.x; xr[1] = v0.y; xr[2] = v0.z;  xr[3] = v0.w;
    xr[4] = v1.x; xr[5] = v1.y; xr[6] = v1.z;  xr[7] = v1.w;
    xr[8] = v2.x; xr[9] = v2.y; xr[10] = v2.z; xr[11] = v2.w;
  }
  for (int kk = 0; kk < 32; ++kk) {
    const int k = kc + kk;
    unsigned short v = 0;
    if (valid) {
      float acc = ip_b[k];
      const float* wr = ip_w + k * C_IN_;
#pragma unroll
      for (int c = 0; c < C_IN_; ++c) acc += xr[c] * wr[c];
      v = f2bf(acc);
    }
    int off = (rl >> 4) * 2048 + (k >> 5) * 512 + ((k & 31) >> 3) * 128
            + (rl & 15) * 8 + (k & 7);
    pk_s[off] = v;
  }
  __syncthreads();
  const float4* s4 = (const float4*)pk_s;
  float4* dst = (float4*)(h_pk + (size_t)(b * 64 + tile4 * 4) * 4096);
#pragma unroll
  for (int q = 0; q < 4; ++q) dst[tid * 4 + q] = s4[tid * 4 + q];
}

// K1 v8 (unchanged): MFMA bf16 GEMM + halo + causal conv + silu -> u (fp32).
__global__ __launch_bounds__(256) void k1_u(
    const char* __restrict__ h_pk, const char* __restrict__ w_pk,
    const float* __restrict__ conv_w, const float* __restrict__ conv_b,
    float* __restrict__ u_out)
{
  __shared__ float xm[67][260];

  const int tile = blockIdx.x;
  const int b    = blockIdx.y;
  const int t0   = tile * 64;
  const int tid  = threadIdx.x;
  const int w    = tid >> 6;
  const int l    = tid & 63;

  {
    const char* achunk = h_pk + (size_t)(b * 64 + tile * 4 + w) * 4096;
    bf16x8 a0 = *(const bf16x8*)(achunk + 0 * 1024 + l * 16);
    bf16x8 a1 = *(const bf16x8*)(achunk + 1 * 1024 + l * 16);
    bf16x8 a2 = *(const bf16x8*)(achunk + 2 * 1024 + l * 16);
    bf16x8 a3 = *(const bf16x8*)(achunk + 3 * 1024 + l * 16);

    const int row_l = w * 16 + (l >> 4) * 4;
#pragma unroll
    for (int nt = 0; nt < 16; ++nt) {
      const char* wb = w_pk + (size_t)nt * 4096 + l * 16;
      bf16x8 b0 = *(const bf16x8*)(wb + 0 * 1024);
      bf16x8 b1 = *(const bf16x8*)(wb + 1 * 1024);
      bf16x8 b2 = *(const bf16x8*)(wb + 2 * 1024);
      bf16x8 b3 = *(const bf16x8*)(wb + 3 * 1024);
      f32x4 acc = {0.f, 0.f, 0.f, 0.f};
      acc = __builtin_amdgcn_mfma_f32_16x16x32_bf16(a0, b0, acc, 0, 0, 0);
      acc = __builtin_amdgcn_mfma_f32_16x16x32_bf16(a1, b1, acc, 0, 0, 0);
      acc = __builtin_amdgcn_mfma_f32_16x16x32_bf16(a2, b2, acc, 0, 0, 0);
      acc = __builtin_amdgcn_mfma_f32_16x16x32_bf16(a3, b3, acc, 0, 0, 0);
      const int col = nt * 16 + (l & 15);
#pragma unroll
      for (int r = 0; r < 4; ++r)
        xm[3 + row_l + r][col] = acc[r];
    }
  }

  {
    const int n = tid;
    float hac[3] = {0.f, 0.f, 0.f};
    if (tile > 0) {
      const char* wrow = w_pk + (size_t)(n >> 4) * 4096 + (n & 15) * 16;
#pragma unroll
      for (int kt = 0; kt < 4; ++kt)
#pragma unroll
        for (int lg = 0; lg < 4; ++lg) {
          u16x8 wv = *(const u16x8*)(wrow + kt * 1024 + lg * 256);
#pragma unroll
          for (int r = 0; r < 3; ++r) {
            const int t = t0 - 3 + r;
            const char* hc = h_pk + (size_t)(b * 64 + (t >> 4)) * 4096;
            u16x8 hv = *(const u16x8*)(hc + kt * 1024 + lg * 256 + (t & 15) * 16);
#pragma unroll
            for (int j = 0; j < 8; ++j) hac[r] += bf2f(hv[j]) * bf2f(wv[j]);
          }
        }
    }
#pragma unroll
    for (int r = 0; r < 3; ++r) xm[r][n] = hac[r];
  }
  __syncthreads();

  {
    const int n = tid;
    const float4 cw = *(const float4*)&conv_w[n * 4];
    const float  cb = conv_b[n];
    float x0 = xm[0][n], x1 = xm[1][n], x2 = xm[2][n];
    for (int i = 0; i < 64; ++i) {
      const int t = t0 + i;
      float x3 = xm[3 + i][n];
      if (t < T_LEN) {
        float s = cb + x0 * cw.x + x1 * cw.y + x2 * cw.z + x3 * cw.w;
        u_out[(((size_t)b * T_LEN + t) << 8) + n] = s * sigmoid_f(s);
      }
      x0 = x1; x1 = x2; x2 = x3;
    }
  }
}

// K3 v7: phase1 dbc = u @ xp[0:24].T; phase2 thread-per-d emits delta/du
// TIME-PACKED bf16 pk[b][t8][d][8]; bm packed pk_bm[b][t8][n][8].
__global__ __launch_bounds__(256) void k3_delta(
    const float* __restrict__ u, const float* __restrict__ x_proj_w,
    const float* __restrict__ dt_proj_w, const float* __restrict__ dt_proj_b,
    unsigned short* __restrict__ pk_delta, unsigned short* __restrict__ pk_du,
    unsigned short* __restrict__ pk_bm)
{
  __shared__ float4 xp4[24][65];
  __shared__ float dt_s[64][9];
  __shared__ float bm_s[64][17];

  const int row0 = blockIdx.x * 64;
  const int tid = threadIdx.x;

  for (int f = tid; f < 24 * 64; f += 256) {
    int c = f >> 6, k4 = f & 63;
    xp4[c][k4] = *(const float4*)&x_proj_w[(size_t)c * 256 + k4 * 4];
  }
  const float4 w0 = *(const float4*)&dt_proj_w[(size_t)tid * 8];
  const float4 w1 = *(const float4*)&dt_proj_w[(size_t)tid * 8 + 4];
  const float bias = dt_proj_b[tid];
  __syncthreads();

  // phase 1
  {
    const int r2 = tid >> 3, cg = tid & 7;
    const int ra = 2 * r2;
    const float4* ua4 = (const float4*)(u + (size_t)(row0 + ra) * 256);
    const float4* ub4 = (const float4*)(u + (size_t)(row0 + ra + 1) * 256);
    float a0 = 0.f, a1 = 0.f, a2 = 0.f, b0 = 0.f, b1 = 0.f, b2 = 0.f;
    for (int k4 = 0; k4 < 64; ++k4) {
      float4 a = ua4[k4], bb = ub4[k4];
      float4 q0 = xp4[cg * 3 + 0][k4];
      float4 q1 = xp4[cg * 3 + 1][k4];
      float4 q2 = xp4[cg * 3 + 2][k4];
      a0 += a.x * q0.x + a.y * q0.y + a.z * q0.z + a.w * q0.w;
      a1 += a.x * q1.x + a.y * q1.y + a.z * q1.z + a.w * q1.w;
      a2 += a.x * q2.x + a.y * q2.y + a.z * q2.z + a.w * q2.w;
      b0 += bb.x * q0.x + bb.y * q0.y + bb.z * q0.z + bb.w * q0.w;
      b1 += bb.x * q1.x + bb.y * q1.y + bb.z * q1.z + bb.w * q1.w;
      b2 += bb.x * q2.x + bb.y * q2.y + bb.z * q2.z + bb.w * q2.w;
    }
    float va[2][3] = {{a0, a1, a2}, {b0, b1, b2}};
#pragma unroll
    for (int rr = 0; rr < 2; ++rr)
#pragma unroll
      for (int c = 0; c < 3; ++c) {
        int col = cg * 3 + c;
        int row = ra + rr;
        if (col < 8) dt_s[row][col] = va[rr][c];
        else bm_s[row][col - 8] = va[rr][c];
      }
  }
  __syncthreads();

  // phase 2: thread = d; 8 groups of 8 t -> one b128 store per array per group
  for (int g = 0; g < 8; ++g) {
    unsigned short pd[8], pu[8];
#pragma unroll
    for (int j = 0; j < 8; ++j) {
      int r = g * 8 + j;
      float pre = bias
        + dt_s[r][0] * w0.x + dt_s[r][1] * w0.y + dt_s[r][2] * w0.z + dt_s[r][3] * w0.w
        + dt_s[r][4] * w1.x + dt_s[r][5] * w1.y + dt_s[r][6] * w1.z + dt_s[r][7] * w1.w;
      float dlt = softplus_f(pre);
      size_t o = (size_t)(row0 + r) * 256 + tid;
      pd[j] = f2bf(dlt);
      pu[j] = f2bf(dlt * u[o]);
    }
    int row = row0 + g * 8;
    int bb_ = row / 1000;
    int t   = row - bb_ * 1000;
    size_t base = (((size_t)bb_ * 125 + (t >> 3)) * 256 + tid) * 8;
    *(u16x8*)&pk_delta[base] = *(u16x8*)pd;
    *(u16x8*)&pk_du[base]    = *(u16x8*)pu;
  }
  if (tid < 16) {
    for (int g = 0; g < 8; ++g) {
      unsigned short pb[8];
#pragma unroll
      for (int j = 0; j < 8; ++j) pb[j] = f2bf(bm_s[g * 8 + j][tid]);
      int row = row0 + g * 8;
      int bb_ = row / 1000;
      int t   = row - bb_ * 1000;
      *(u16x8*)&pk_bm[(((size_t)bb_ * 125 + (t >> 3)) * 16 + tid) * 8] = *(u16x8*)pb;
    }
  }
}

// K4 v9: time-packed b128 reads + RAW v_exp_f32 (arg provably in [-130,0] so
// the libm overflow/denorm fixup around exp2f is dead weight -- ~6 insts/step).
__global__ __launch_bounds__(256) void k4_scan(
    const unsigned short* __restrict__ pk_delta,
    const unsigned short* __restrict__ pk_du,
    const unsigned short* __restrict__ pk_bm,
    const float* __restrict__ A_log, float* __restrict__ state_out)
{
  const int d0 = blockIdx.x * 16;
  const int b  = blockIdx.y;
  const int tid = threadIdx.x;
  const int dl = tid >> 4;
  const int n  = tid & 15;
  const int d  = d0 + dl;

  const float A2 = -expf(A_log[(size_t)d * 16 + n]) * 1.4426950408889634f;
  float s = 0.f;

  const unsigned short* dp = pk_delta + ((size_t)b * 125 * 256 + d) * 8;
  const unsigned short* xp = pk_du    + ((size_t)b * 125 * 256 + d) * 8;
  const unsigned short* bp = pk_bm    + ((size_t)b * 125 * 16 + n) * 8;

#pragma unroll 2
  for (int t8 = 0; t8 < 125; ++t8) {
    u16x8 dv = *(const u16x8*)(dp + (size_t)t8 * 2048);
    u16x8 xv = *(const u16x8*)(xp + (size_t)t8 * 2048);
    u16x8 bv = *(const u16x8*)(bp + (size_t)t8 * 128);
#pragma unroll
    for (int j = 0; j < 8; ++j)
      s = fast_exp2(bf2f(dv[j]) * A2) * s + bf2f(xv[j]) * bf2f(bv[j]);
  }
  state_out[((size_t)b * 256 + d) * 16 + n] = s;
}

// K5: per-batch head (unchanged).
__global__ __launch_bounds__(256) void k5_head(
    const float* __restrict__ x, const float* __restrict__ ip_w,
    const float* __restrict__ ip_b, const float* __restrict__ in_proj_w,
    const float* __restrict__ x_proj_w, const float* __restrict__ u,
    const float* __restrict__ state, const float* __restrict__ D_skip,
    const float* __restrict__ out_proj_w, const float* __restrict__ fc1_w,
    const float* __restrict__ fc1_b, const float* __restrict__ fc2_w,
    const float* __restrict__ fc2_b, float* __restrict__ out)
{
  const int b = blockIdx.x, tid = threadIdx.x;
  __shared__ float hl[128], ul[256], zs[256], cm[16], yv[256], ov[128], hid[64];
  if (tid < 128) {
    float acc = ip_b[tid];
    const float* xr = x + ((size_t)b * T_LEN + (T_LEN - 1)) * C_IN_;
#pragma unroll
    for (int c = 0; c < C_IN_; ++c) acc += xr[c] * ip_w[tid * C_IN_ + c];
    hl[tid] = acc;
  }
  ul[tid] = u[((size_t)b * T_LEN + (T_LEN - 1)) * 256 + tid];
  __syncthreads();
  {
    float acc = 0.f;
    const float4* wv = (const float4*)(in_proj_w + (size_t)(256 + tid) * 128);
    const float4* h4 = (const float4*)hl;
    for (int k = 0; k < 32; ++k) {
      float4 a = wv[k], c = h4[k];
      acc += c.x * a.x + c.y * a.y + c.z * a.z + c.w * a.w;
    }
    zs[tid] = acc * sigmoid_f(acc);
  }
  if (tid < 16) {
    float acc = 0.f;
    const float4* wv = (const float4*)(x_proj_w + (size_t)(24 + tid) * 256);
    const float4* u4 = (const float4*)ul;
    for (int k = 0; k < 64; ++k) {
      float4 a = wv[k], c = u4[k];
      acc += c.x * a.x + c.y * a.y + c.z * a.z + c.w * a.w;
    }
    cm[tid] = acc;
  }
  __syncthreads();
  {
    const float* st = state + ((size_t)b * 256 + tid) * 16;
    float acc = 0.f;
#pragma unroll
    for (int n = 0; n < 16; ++n) acc += st[n] * cm[n];
    yv[tid] = (acc + ul[tid] * D_skip[tid]) * zs[tid];
  }
  __syncthreads();
  if (tid < 128) {
    float acc = 0.f;
    const float4* wv = (const float4*)(out_proj_w + (size_t)tid * 256);
    const float4* y4 = (const float4*)yv;
    for (int k = 0; k < 64; ++k) {
      float4 a = wv[k], c = y4[k];
      acc += c.x * a.x + c.y * a.y + c.z * a.z + c.w * a.w;
    }
    ov[tid] = acc;
  }
  __syncthreads();
  if (tid < 64) {
    float acc = fc1_b[tid];
    const float4* wv = (const float4*)(fc1_w + (size_t)tid * 128);
    const float4* o4 = (const float4*)ov;
    for (int k = 0; k < 32; ++k) {
      float4 a = wv[k], c = o4[k];
      acc += c.x * a.x + c.y * a.y + c.z * a.z + c.w * a.w;
    }
    hid[tid] = fmaxf(acc, 0.f);
  }
  __syncthreads();
  if (tid < N_CLS) {
    float acc = fc2_b[tid];
    const float* wv = fc2_w + (size_t)tid * 64;
    for (int k = 0; k < 64; ++k) acc += hid[k] * wv[k];
    out[b * N_CLS + tid] = acc;
  }
}

extern "C" void kernel_launch(void* const* d_in, const int* in_sizes, int n_in,
                              void* d_out, int out_size, void* d_ws, size_t ws_size,
                              hipStream_t stream) {
  (void)in_sizes; (void)n_in; (void)out_size; (void)ws_size;
  const float* x         = (const float*)d_in[0];
  const float* ip_w      = (const float*)d_in[1];
  const float* ip_b      = (const float*)d_in[2];
  const float* in_proj_w = (const float*)d_in[3];
  const float* conv_w    = (const float*)d_in[4];
  const float* conv_b    = (const float*)d_in[5];
  const float* x_proj_w  = (const float*)d_in[6];
  const float* dt_proj_w = (const float*)d_in[7];
  const float* dt_proj_b = (const float*)d_in[8];
  const float* A_log     = (const float*)d_in[9];
  const float* D_skip    = (const float*)d_in[10];
  const float* out_proj_w= (const float*)d_in[11];
  const float* fc1_w     = (const float*)d_in[12];
  const float* fc1_b     = (const float*)d_in[13];
  const float* fc2_w     = (const float*)d_in[14];
  const float* fc2_b     = (const float*)d_in[15];
  float* out = (float*)d_out;

  float* u              = (float*)d_ws;                            // 65.5 MB
  unsigned short* delta = (unsigned short*)(u + (size_t)16384000); // 32.8 MB packed
  unsigned short* du    = delta + (size_t)16384000;                // 32.8 MB packed
  unsigned short* bm    = du + (size_t)16384000;                   // 2.0 MB packed
  float* state          = (float*)(bm + (size_t)1024000);          // 1.0 MB
  char* h_pk            = (char*)(state + (size_t)262144);         // 16.8 MB
  char* w_pk            = h_pk + (size_t)64 * 64 * 4096;           // 64 KB

  k0_prep<<<dim3(17, 64), 256, 0, stream>>>(x, ip_w, ip_b, in_proj_w, h_pk, w_pk);
  k1_u<<<dim3(16, 64), 256, 0, stream>>>(h_pk, w_pk, conv_w, conv_b, u);
  k3_delta<<<1000, 256, 0, stream>>>(u, x_proj_w, dt_proj_w, dt_proj_b, delta, du, bm);
  k4_scan<<<dim3(16, 64), 256, 0, stream>>>(delta, du, bm, A_log, state);
  k5_head<<<64, 256, 0, stream>>>(x, ip_w, ip_b, in_proj_w, x_proj_w, u, state,
                                  D_skip, out_proj_w, fc1_w, fc1_b, fc2_w, fc2_b, out);
}